// Round 1
// baseline (201.243 us; speedup 1.0000x reference)
//
#include <hip/hip_runtime.h>

typedef unsigned short ushort_t;

#define M_DIM 1024   // 2*512 rows of x
#define N_DIM 4096   // OUT_F
#define K_DIM 4096   // IN_F
#define NFREQ 10000
constexpr float SCALE = 150.0f / 64.0f;   // 150 / sqrt(4096)

typedef __bf16 bf16x8_t  __attribute__((ext_vector_type(8)));
typedef float  f32x16_t  __attribute__((ext_vector_type(16)));

__device__ inline ushort_t f2bf(float f) {
  union { float f; unsigned u; } v; v.f = f;
  unsigned r = v.u + 0x7fffu + ((v.u >> 16) & 1u);   // RNE
  return (ushort_t)(r >> 16);
}

// ---------------------------------------------------------------------------
// Kernel 0 (NEW): one-shot entry preparation, 64 blocks (one per 64-col group).
// Does the former build_w4 phases 1-3 exactly ONCE per column group instead of
// 16x (once per row-chunk block): scan indices, bucket by column, prefix-sum,
// sort-scatter, last-wins dedup. Writes sorted entries + cstart to workspace.
// ---------------------------------------------------------------------------
__global__ __launch_bounds__(256) void prep_entries(
    const float* __restrict__ spectrum,
    const int* __restrict__ idx,          // [2][NFREQ]: row 0 = r (out), row 1 = c (in)
    uint2* __restrict__ ent,              // [64][CAP]
    int* __restrict__ cst) {              // [64][72], [g][0..64] = cstart, [g][64] = n
  constexpr int CAP = 1024;
  __shared__ unsigned e_raw[CAP];   // (dc<<26)|(j<<12)|r
  __shared__ float    v_raw[CAP];
  __shared__ uint2    ev_srt[CAP];  // .x = packed meta, .y = float bits
  __shared__ int cnt;
  __shared__ int cstart[65];
  __shared__ int coff[64];
  __shared__ int ccnt[64];

  const int tid = threadIdx.x;
  const int g = blockIdx.x;

  if (tid == 0) cnt = 0;
  if (tid < 64) ccnt[tid] = 0;
  __syncthreads();

  // Phase 1: collect this group's entries
  for (int j = tid; j < NFREQ; j += 256) {
    int c = idx[NFREQ + j];
    if ((c >> 6) == g) {
      int p = atomicAdd(&cnt, 1);
      if (p < CAP) {
        e_raw[p] = ((unsigned)(c & 63) << 26) | ((unsigned)j << 12) | (unsigned)idx[j];
        v_raw[p] = spectrum[j];
        atomicAdd(&ccnt[c & 63], 1);
      }
    }
  }
  __syncthreads();
  const int n = cnt < CAP ? cnt : CAP;

  // Phase 2: prefix sum over 64 column counts (wave 0), then scatter sorted
  if (tid < 64) {
    int v = ccnt[tid];
    int s = v;
    for (int d = 1; d < 64; d <<= 1) {
      int o = __shfl_up(s, d, 64);
      if (tid >= d) s += o;
    }
    cstart[tid + 1] = s;
    if (tid == 0) cstart[0] = 0;
    coff[tid] = s - v;   // exclusive
  }
  __syncthreads();
  for (int e = tid; e < n; e += 256) {
    unsigned w = e_raw[e];
    int dc = w >> 26;
    int p = atomicAdd(&coff[dc], 1);
    ev_srt[p] = make_uint2(w, __float_as_uint(v_raw[e]));
  }
  __syncthreads();

  // Phase 3: last-wins dedup within each column bucket
  for (int e = tid; e < n; e += 256) {
    uint2 ev = ev_srt[e];
    int dc = ev.x >> 26;
    unsigned r = ev.x & 0xFFFu, j = (ev.x >> 12) & 0x3FFFu;
    int s0 = cstart[dc], e0 = cstart[dc + 1];
    bool dead = false;
    for (int p = s0; p < e0; ++p) {
      unsigned w2 = ev_srt[p].x;
      if ((w2 & 0xFFFu) == r && ((w2 >> 12) & 0x3FFFu) > j) dead = true;
    }
    if (dead) ev_srt[e].y = 0u;   // +0.0f: additive no-op == excluded
  }
  __syncthreads();

  // Write out sorted+deduped entries and per-column starts
  for (int e = tid; e < n; e += 256) ent[g * CAP + e] = ev_srt[e];
  if (tid < 65) cst[g * 72 + tid] = cstart[tid];
}

// ---------------------------------------------------------------------------
// Kernel 1 (streamlined): W' = bf16( weight + s * iwht(scatter) ) using the
// precomputed entry lists. One barrier, no atomics, no sort -> pure streaming.
// x fp32->bf16 stays folded in as grid-y slice 16.
// ---------------------------------------------------------------------------
__global__ __launch_bounds__(256) void apply_w(
    const float* __restrict__ weight,
    const float* __restrict__ x,
    const uint2* __restrict__ ent,
    const int* __restrict__ cst,
    ushort_t* __restrict__ wb,
    ushort_t* __restrict__ xb) {
  // ---- folded cvt_x slice ----
  if (blockIdx.y == 16) {
    int flat = blockIdx.x * 256 + threadIdx.x;    // 16384 threads
#pragma unroll 4
    for (int k = 0; k < 64; ++k) {
      int i = flat + k * 16384;                   // M*K/4 = 1048576 float4s
      float4 v = ((const float4*)x)[i];
      ushort4 o;
      o.x = f2bf(v.x); o.y = f2bf(v.y); o.z = f2bf(v.z); o.w = f2bf(v.w);
      ((ushort4*)xb)[i] = o;
    }
    return;
  }

  constexpr int CAP = 1024;
  __shared__ uint2 ev[CAP];
  __shared__ int cstart[65];
  __shared__ unsigned walsh16[16];  // walsh16[m] bit j = parity(j & m)

  const int tid = threadIdx.x;
  const int g   = blockIdx.x;
  const int ci0 = g * 64;
  const int o0  = blockIdx.y * 256;

  const int n = cst[g * 72 + 64];   // wave-uniform, L2-resident
  if (tid < 65) cstart[tid] = cst[g * 72 + tid];
  if (tid < 16) {
    unsigned m = tid;
    unsigned w = (m & 1 ? 0xAAAAu : 0u) ^ (m & 2 ? 0xCCCCu : 0u)
               ^ (m & 4 ? 0xF0F0u : 0u) ^ (m & 8 ? 0xFF00u : 0u);
    walsh16[m] = w;
  }
  for (int e = tid; e < n; e += 256) ev[e] = ent[g * CAP + e];
  __syncthreads();

  // thread = 4 consecutive cols x 16 CONTIGUOUS rows, entry-outer.
  const int dc0   = (tid & 15) * 4;
  const int rof   = tid >> 4;
  const int obase = o0 + rof * 16;

  float acc[4][16];
#pragma unroll
  for (int c = 0; c < 4; ++c)
#pragma unroll
    for (int j = 0; j < 16; ++j) acc[c][j] = 0.0f;

#pragma unroll
  for (int c = 0; c < 4; ++c) {
    const int s = cstart[dc0 + c], e = cstart[dc0 + c + 1];
    for (int p = s; p < e; ++p) {
      uint2 evv = ev[p];                          // one ds_read_b64 per entry
      unsigned r = evv.x & 0xFFFu;
      unsigned W = walsh16[r & 15u];              // 16-row sign pattern
      unsigned sx = evv.y ^ ((unsigned)(__popc(obase & r) & 1) << 31);  // ±v base sign
#pragma unroll
      for (int j = 0; j < 16; ++j) {
        acc[c][j] += __uint_as_float(sx ^ ((W << (31 - j)) & 0x80000000u));
      }
    }
  }

  // Epilogue: FULL unroll so all acc indices are compile-time (VGPR-resident;
  // partial unroll demotes acc to scratch — R4 regression).
  size_t gaddr = (size_t)obase * K_DIM + ci0 + dc0;
#pragma unroll
  for (int j = 0; j < 16; ++j) {
    float4 w4 = *(const float4*)&weight[gaddr];
    ushort4 ov;
    ov.x = f2bf(w4.x + SCALE * acc[0][j]);
    ov.y = f2bf(w4.y + SCALE * acc[1][j]);
    ov.z = f2bf(w4.z + SCALE * acc[2][j]);
    ov.w = f2bf(w4.w + SCALE * acc[3][j]);
    *(ushort4*)&wb[gaddr] = ov;
    gaddr += K_DIM;
  }
}

// ---------------------------------------------------------------------------
// Kernel 2: C[M,N] = A[M,K] * B[N,K]^T  (bf16 in, fp32 out), split-K via z.
// 128x128 tile, BK=64, XOR-swizzled LDS, global_load_lds 16B staging,
// inner op = mfma_f32_32x32x16_bf16 (wave tile 64x64 as 2x2 of 32x32).
// A/B frag: row = lane&31, k = (lane>>5)*8 + t (one b128 per frag).
// C/D: col = lane&31, row = (reg&3) + 8*(reg>>2) + 4*(lane>>5).
// ---------------------------------------------------------------------------
__global__ __launch_bounds__(256) void gemm_bt(
    const ushort_t* __restrict__ A,   // xb [M,K]
    const ushort_t* __restrict__ B,   // wb [N,K]
    float* __restrict__ C0,
    float* __restrict__ C1,
    int klen) {
  constexpr int BM = 128, BN = 128, BK = 64;
  __shared__ __align__(16) ushort_t As[BM * BK];   // 16 KB
  __shared__ __align__(16) ushort_t Bs[BN * BK];   // 16 KB

  const int tid  = threadIdx.x;
  const int wave = tid >> 6, lane = tid & 63;
  const int wrow = wave >> 1, wcol = wave & 1;
  const int l32  = lane & 31, half = lane >> 5;
  const int bm = blockIdx.y * BM, bn = blockIdx.x * BN;
  const int kbeg = blockIdx.z * klen;
  float* __restrict__ dst = blockIdx.z == 0
      ? C0 : C1 + (size_t)(blockIdx.z - 1) * M_DIM * N_DIM;

  const int srow8 = lane >> 3;          // staging: row within chunk, 0..7
  const int sq    = lane & 7;           // 16B slot within row, 0..7

  f32x16_t acc[2][2] = {};

  for (int kt = kbeg; kt < kbeg + klen; kt += BK) {
#pragma unroll
    for (int c = 0; c < 4; ++c) {
      int ch = wave * 4 + c;            // wave-uniform
      int gr = ch * 8 + srow8;          // tile row 0..127
      int qg = sq ^ (gr & 7);           // swizzled source quad
      const ushort_t* ga = A + (size_t)(bm + gr) * K_DIM + kt + qg * 8;
      __builtin_amdgcn_global_load_lds(
          (const __attribute__((address_space(1))) void*)ga,
          (__attribute__((address_space(3))) void*)&As[ch * 512], 16, 0, 0);
      const ushort_t* gb = B + (size_t)(bn + gr) * K_DIM + kt + qg * 8;
      __builtin_amdgcn_global_load_lds(
          (const __attribute__((address_space(1))) void*)gb,
          (__attribute__((address_space(3))) void*)&Bs[ch * 512], 16, 0, 0);
    }
    __syncthreads();

    // fragment loads: frag (mi,h) = A rows [wrow*64+mi*32 .. +32), k half*8+h*16
    bf16x8_t af[2][4], bfr[2][4];
#pragma unroll
    for (int mi = 0; mi < 2; ++mi) {
#pragma unroll
      for (int h = 0; h < 4; ++h) {
        int q = h * 2 + half;           // 16B slot index along k
        int ar = wrow * 64 + mi * 32 + l32;
        af[mi][h]  = *(const bf16x8_t*)&As[ar * BK + ((q ^ (ar & 7)) * 8)];
        int br = wcol * 64 + mi * 32 + l32;
        bfr[mi][h] = *(const bf16x8_t*)&Bs[br * BK + ((q ^ (br & 7)) * 8)];
      }
    }
#pragma unroll
    for (int h = 0; h < 4; ++h)
#pragma unroll
      for (int mi = 0; mi < 2; ++mi)
#pragma unroll
        for (int nj = 0; nj < 2; ++nj)
          acc[mi][nj] = __builtin_amdgcn_mfma_f32_32x32x16_bf16(
              af[mi][h], bfr[nj][h], acc[mi][nj], 0, 0, 0);
    __syncthreads();
  }

  // epilogue: col = lane&31, row = (reg&3) + 8*(reg>>2) + 4*half
#pragma unroll
  for (int mi = 0; mi < 2; ++mi) {
#pragma unroll
    for (int nj = 0; nj < 2; ++nj) {
      int col  = bn + wcol * 64 + nj * 32 + l32;
      int rwb  = bm + wrow * 64 + mi * 32 + 4 * half;
#pragma unroll
      for (int reg = 0; reg < 16; ++reg) {
        int row = rwb + (reg & 3) + 8 * (reg >> 2);
        dst[(size_t)row * N_DIM + col] = acc[mi][nj][reg];
      }
    }
  }
}

// ---------------------------------------------------------------------------
// Kernel 3: out += sum of npart partial arrays (float4)
// ---------------------------------------------------------------------------
__global__ __launch_bounds__(256) void reduce_n(float* __restrict__ out,
                                                const float* __restrict__ part,
                                                int npart) {
  int i = blockIdx.x * 256 + threadIdx.x;
  float4 a = ((const float4*)out)[i];
  for (int t = 0; t < npart; ++t) {
    float4 b = ((const float4*)(part + (size_t)t * M_DIM * N_DIM))[i];
    a.x += b.x; a.y += b.y; a.z += b.z; a.w += b.w;
  }
  ((float4*)out)[i] = a;
}

extern "C" void kernel_launch(void* const* d_in, const int* in_sizes, int n_in,
                              void* d_out, int out_size, void* d_ws, size_t ws_size,
                              hipStream_t stream) {
  const float* x        = (const float*)d_in[0];   // [2,512,4096]
  const float* weight   = (const float*)d_in[1];   // [4096,4096]
  const float* spectrum = (const float*)d_in[2];   // [10000]
  const int*   indices  = (const int*)d_in[3];     // [2,10000]
  float* out = (float*)d_out;                      // [2,512,4096]

  char* ws = (char*)d_ws;
  const size_t WB_BYTES  = (size_t)N_DIM * K_DIM * 2;   // 32 MB
  const size_t XB_BYTES  = (size_t)M_DIM * K_DIM * 2;   //  8 MB
  const size_t P1_BYTES  = (size_t)M_DIM * N_DIM * 4;   // 16 MB per partial
  const size_t ENT_BYTES = (size_t)64 * 1024 * sizeof(uint2);  // 512 KB

  ushort_t* wb = (ushort_t*)ws;
  ushort_t* xb = (ushort_t*)(ws + WB_BYTES);
  // Entry scratch ALIASES the partial region: prep writes + apply reads it
  // strictly before gemm_bt writes part (stream-ordered), so this is safe and
  // costs no extra workspace.
  char* scratch = ws + WB_BYTES + XB_BYTES;
  uint2* ent = (uint2*)scratch;
  int*   cst = (int*)(scratch + ENT_BYTES);
  float* part = (float*)scratch;

  int zsplit = (ws_size >= WB_BYTES + XB_BYTES + 3 * P1_BYTES) ? 4
             : (ws_size >= WB_BYTES + XB_BYTES + P1_BYTES)     ? 2 : 1;

  // one-shot entry prep (64 blocks), then streaming W'-build + x-convert
  prep_entries<<<64, 256, 0, stream>>>(spectrum, indices, ent, cst);
  apply_w<<<dim3(64, 17), 256, 0, stream>>>(weight, x, ent, cst, wb, xb);

  gemm_bt<<<dim3(N_DIM / 128, M_DIM / 128, zsplit), 256, 0, stream>>>(
      xb, wb, out, part, K_DIM / zsplit);
  if (zsplit > 1)
    reduce_n<<<(M_DIM * N_DIM / 4) / 256, 256, 0, stream>>>(out, part, zsplit - 1);
}

// Round 2
// 199.930 us; speedup vs baseline: 1.0066x; 1.0066x over previous
//
#include <hip/hip_runtime.h>

typedef unsigned short ushort_t;

#define M_DIM 1024   // 2*512 rows of x
#define N_DIM 4096   // OUT_F
#define K_DIM 4096   // IN_F
#define NFREQ 10000
constexpr float SCALE = 150.0f / 64.0f;   // 150 / sqrt(4096)

typedef __bf16 bf16x8_t  __attribute__((ext_vector_type(8)));
typedef float  f32x16_t  __attribute__((ext_vector_type(16)));

__device__ inline ushort_t f2bf(float f) {
  union { float f; unsigned u; } v; v.f = f;
  unsigned r = v.u + 0x7fffu + ((v.u >> 16) & 1u);   // RNE
  return (ushort_t)(r >> 16);
}

// ---------------------------------------------------------------------------
// Kernel 1: W' = bf16( weight + s * iwht(scatter(spectrum,idx)) ), plus
// x fp32->bf16 folded in as grid-y slice 16.  (R0 structure — the 4-kernel
// split regressed; phases 1-3 are NOT the bottleneck.)
// R2 change: MLP fix. The old epilogue interleaved load->cvt->store (1 load
// in flight/thread -> ~1.9 TB/s latency ceiling, measured 1.55). Now all 16
// weight float4s are issued into VGPRs BEFORE the LDS accumulation pass, so
// 256 B/thread stay in flight under phase-4 VALU work. Same treatment (8-deep
// prefetch) for the x-convert slice.
// ---------------------------------------------------------------------------
__global__ __launch_bounds__(256) void build_w4(
    const float* __restrict__ weight,
    const float* __restrict__ spectrum,
    const int* __restrict__ idx,          // [2][NFREQ]: row 0 = r (out), row 1 = c (in)
    const float* __restrict__ x,
    ushort_t* __restrict__ wb,
    ushort_t* __restrict__ xb) {
  // ---- folded cvt_x slice ----
  if (blockIdx.y == 16) {
    int flat = blockIdx.x * 256 + threadIdx.x;    // 16384 threads
    for (int kk = 0; kk < 8; ++kk) {
      float4 v[8];
#pragma unroll
      for (int u = 0; u < 8; ++u)
        v[u] = ((const float4*)x)[flat + (kk * 8 + u) * 16384];
#pragma unroll
      for (int u = 0; u < 8; ++u) {
        ushort4 o;
        o.x = f2bf(v[u].x); o.y = f2bf(v[u].y);
        o.z = f2bf(v[u].z); o.w = f2bf(v[u].w);
        ((ushort4*)xb)[flat + (kk * 8 + u) * 16384] = o;
      }
    }
    return;
  }

  constexpr int CAP = 1024;
  __shared__ unsigned e_raw[CAP];   // (dc<<26)|(j<<12)|r
  __shared__ float    v_raw[CAP];
  __shared__ uint2    ev_srt[CAP];  // .x = packed meta, .y = float bits
  __shared__ int cnt;
  __shared__ int cstart[65];
  __shared__ int coff[64];
  __shared__ int ccnt[64];
  __shared__ unsigned walsh16[16];  // walsh16[m] bit j = parity(j & m)

  const int tid = threadIdx.x;
  const int ci0 = blockIdx.x * 64;
  const int o0  = blockIdx.y * 256;

  if (tid == 0) cnt = 0;
  if (tid < 64) ccnt[tid] = 0;
  if (tid < 16) {
    unsigned m = tid;
    unsigned w = (m & 1 ? 0xAAAAu : 0u) ^ (m & 2 ? 0xCCCCu : 0u)
               ^ (m & 4 ? 0xF0F0u : 0u) ^ (m & 8 ? 0xFF00u : 0u);
    walsh16[m] = w;
  }
  __syncthreads();

  // Phase 1: collect this group's entries
  for (int j = tid; j < NFREQ; j += 256) {
    int c = idx[NFREQ + j];
    if ((c >> 6) == (int)blockIdx.x) {
      int p = atomicAdd(&cnt, 1);
      if (p < CAP) {
        e_raw[p] = ((unsigned)(c & 63) << 26) | ((unsigned)j << 12) | (unsigned)idx[j];
        v_raw[p] = spectrum[j];
        atomicAdd(&ccnt[c & 63], 1);
      }
    }
  }
  __syncthreads();
  const int n = cnt < CAP ? cnt : CAP;

  // Phase 2: prefix sum over 64 column counts (wave 0), then scatter sorted
  if (tid < 64) {
    int v = ccnt[tid];
    int s = v;
    for (int d = 1; d < 64; d <<= 1) {
      int o = __shfl_up(s, d, 64);
      if (tid >= d) s += o;
    }
    cstart[tid + 1] = s;
    if (tid == 0) cstart[0] = 0;
    coff[tid] = s - v;   // exclusive
  }
  __syncthreads();
  for (int e = tid; e < n; e += 256) {
    unsigned w = e_raw[e];
    int dc = w >> 26;
    int p = atomicAdd(&coff[dc], 1);
    ev_srt[p] = make_uint2(w, __float_as_uint(v_raw[e]));
  }
  __syncthreads();

  // Phase 3: last-wins dedup within each column bucket (LDS-local)
  for (int e = tid; e < n; e += 256) {
    uint2 ev = ev_srt[e];
    int dc = ev.x >> 26;
    unsigned r = ev.x & 0xFFFu, j = (ev.x >> 12) & 0x3FFFu;
    int s0 = cstart[dc], e0 = cstart[dc + 1];
    bool dead = false;
    for (int p = s0; p < e0; ++p) {
      unsigned w2 = ev_srt[p].x;
      if ((w2 & 0xFFFu) == r && ((w2 >> 12) & 0x3FFFu) > j) dead = true;
    }
    if (dead) ev_srt[e].y = 0u;   // +0.0f: additive no-op == excluded
  }
  __syncthreads();

  // Phase 4: thread = 4 consecutive cols x 16 CONTIGUOUS rows, entry-outer.
  const int dc0   = (tid & 15) * 4;
  const int rof   = tid >> 4;
  const int obase = o0 + rof * 16;

  // Issue ALL 16 weight loads first: 256 B/thread in flight, latency hidden
  // under the LDS accumulation below (loads have no dependence on it).
  const size_t gaddr = (size_t)obase * K_DIM + ci0 + dc0;
  float4 wv[16];
#pragma unroll
  for (int j = 0; j < 16; ++j)
    wv[j] = *(const float4*)&weight[gaddr + (size_t)j * K_DIM];

  float acc[4][16];
#pragma unroll
  for (int c = 0; c < 4; ++c)
#pragma unroll
    for (int j = 0; j < 16; ++j) acc[c][j] = 0.0f;

#pragma unroll
  for (int c = 0; c < 4; ++c) {
    const int s = cstart[dc0 + c], e = cstart[dc0 + c + 1];
    for (int p = s; p < e; ++p) {
      uint2 ev = ev_srt[p];                       // one ds_read_b64 per entry
      unsigned r = ev.x & 0xFFFu;
      unsigned W = walsh16[r & 15u];              // 16-row sign pattern
      unsigned sx = ev.y ^ ((unsigned)(__popc(obase & r) & 1) << 31);  // ±v base sign
#pragma unroll
      for (int j = 0; j < 16; ++j) {
        acc[c][j] += __uint_as_float(sx ^ ((W << (31 - j)) & 0x80000000u));
      }
    }
  }

  // Combine + store. FULL unroll: all wv/acc indices compile-time (VGPR-
  // resident; partial unroll demotes to scratch — R4 regression).
#pragma unroll
  for (int j = 0; j < 16; ++j) {
    ushort4 ov;
    ov.x = f2bf(wv[j].x + SCALE * acc[0][j]);
    ov.y = f2bf(wv[j].y + SCALE * acc[1][j]);
    ov.z = f2bf(wv[j].z + SCALE * acc[2][j]);
    ov.w = f2bf(wv[j].w + SCALE * acc[3][j]);
    *(ushort4*)&wb[gaddr + (size_t)j * K_DIM] = ov;
  }
}

// ---------------------------------------------------------------------------
// Kernel 2: C[M,N] = A[M,K] * B[N,K]^T  (bf16 in, fp32 out), split-K via z.
// 128x128 tile, BK=64, XOR-swizzled LDS, global_load_lds 16B staging,
// inner op = mfma_f32_32x32x16_bf16 (wave tile 64x64 as 2x2 of 32x32).
// A/B frag: row = lane&31, k = (lane>>5)*8 + t (one b128 per frag).
// C/D: col = lane&31, row = (reg&3) + 8*(reg>>2) + 4*(lane>>5).
// R2 change: XCD-aware 2D-chunk blockIdx swizzle (T1). The 32x8 xy-grid is
// split into 8 chunks of 8x*4y; chunk = fid&7 matches the round-robin
// blockIdx->XCD mapping, so one XCD's 32 blocks share 4 A-panels + 8 B-panels
// (3 MB, fits the 4 MB per-XCD L2) instead of streaming the full B.
// ---------------------------------------------------------------------------
__global__ __launch_bounds__(256) void gemm_bt(
    const ushort_t* __restrict__ A,   // xb [M,K]
    const ushort_t* __restrict__ B,   // wb [N,K]
    float* __restrict__ C0,
    float* __restrict__ C1,
    int klen) {
  constexpr int BM = 128, BN = 128, BK = 64;
  __shared__ __align__(16) ushort_t As[BM * BK];   // 16 KB
  __shared__ __align__(16) ushort_t Bs[BN * BK];   // 16 KB

  const int tid  = threadIdx.x;
  const int wave = tid >> 6, lane = tid & 63;
  const int wrow = wave >> 1, wcol = wave & 1;
  const int l32  = lane & 31, half = lane >> 5;

  // XCD-aware swizzle (bijective on the fixed 32x8 xy-grid)
  const int fid = blockIdx.y * 32 + blockIdx.x;    // 0..255 within z-slice
  const int xcd = fid & 7, w8 = fid >> 3;          // xcd chunk, index in chunk
  const int sx = w8 & 7, sy = w8 >> 3;             // 8x * 4y within chunk
  const int cx = xcd & 3, cy = xcd >> 2;           // chunk grid 4x * 2y
  const int bn = (cx * 8 + sx) * BN;
  const int bm = (cy * 4 + sy) * BM;

  const int kbeg = blockIdx.z * klen;
  float* __restrict__ dst = blockIdx.z == 0
      ? C0 : C1 + (size_t)(blockIdx.z - 1) * M_DIM * N_DIM;

  const int srow8 = lane >> 3;          // staging: row within chunk, 0..7
  const int sq    = lane & 7;           // 16B slot within row, 0..7

  f32x16_t acc[2][2] = {};

  for (int kt = kbeg; kt < kbeg + klen; kt += BK) {
#pragma unroll
    for (int c = 0; c < 4; ++c) {
      int ch = wave * 4 + c;            // wave-uniform
      int gr = ch * 8 + srow8;          // tile row 0..127
      int qg = sq ^ (gr & 7);           // swizzled source quad
      const ushort_t* ga = A + (size_t)(bm + gr) * K_DIM + kt + qg * 8;
      __builtin_amdgcn_global_load_lds(
          (const __attribute__((address_space(1))) void*)ga,
          (__attribute__((address_space(3))) void*)&As[ch * 512], 16, 0, 0);
      const ushort_t* gb = B + (size_t)(bn + gr) * K_DIM + kt + qg * 8;
      __builtin_amdgcn_global_load_lds(
          (const __attribute__((address_space(1))) void*)gb,
          (__attribute__((address_space(3))) void*)&Bs[ch * 512], 16, 0, 0);
    }
    __syncthreads();

    // fragment loads: frag (mi,h) = A rows [wrow*64+mi*32 .. +32), k half*8+h*16
    bf16x8_t af[2][4], bfr[2][4];
#pragma unroll
    for (int mi = 0; mi < 2; ++mi) {
#pragma unroll
      for (int h = 0; h < 4; ++h) {
        int q = h * 2 + half;           // 16B slot index along k
        int ar = wrow * 64 + mi * 32 + l32;
        af[mi][h]  = *(const bf16x8_t*)&As[ar * BK + ((q ^ (ar & 7)) * 8)];
        int br = wcol * 64 + mi * 32 + l32;
        bfr[mi][h] = *(const bf16x8_t*)&Bs[br * BK + ((q ^ (br & 7)) * 8)];
      }
    }
#pragma unroll
    for (int h = 0; h < 4; ++h)
#pragma unroll
      for (int mi = 0; mi < 2; ++mi)
#pragma unroll
        for (int nj = 0; nj < 2; ++nj)
          acc[mi][nj] = __builtin_amdgcn_mfma_f32_32x32x16_bf16(
              af[mi][h], bfr[nj][h], acc[mi][nj], 0, 0, 0);
    __syncthreads();
  }

  // epilogue: col = lane&31, row = (reg&3) + 8*(reg>>2) + 4*half
#pragma unroll
  for (int mi = 0; mi < 2; ++mi) {
#pragma unroll
    for (int nj = 0; nj < 2; ++nj) {
      int col  = bn + wcol * 64 + nj * 32 + l32;
      int rwb  = bm + wrow * 64 + mi * 32 + 4 * half;
#pragma unroll
      for (int reg = 0; reg < 16; ++reg) {
        int row = rwb + (reg & 3) + 8 * (reg >> 2);
        dst[(size_t)row * N_DIM + col] = acc[mi][nj][reg];
      }
    }
  }
}

// ---------------------------------------------------------------------------
// Kernel 3: out += sum of npart partial arrays (float4)
// ---------------------------------------------------------------------------
__global__ __launch_bounds__(256) void reduce_n(float* __restrict__ out,
                                                const float* __restrict__ part,
                                                int npart) {
  int i = blockIdx.x * 256 + threadIdx.x;
  float4 a = ((const float4*)out)[i];
  for (int t = 0; t < npart; ++t) {
    float4 b = ((const float4*)(part + (size_t)t * M_DIM * N_DIM))[i];
    a.x += b.x; a.y += b.y; a.z += b.z; a.w += b.w;
  }
  ((float4*)out)[i] = a;
}

extern "C" void kernel_launch(void* const* d_in, const int* in_sizes, int n_in,
                              void* d_out, int out_size, void* d_ws, size_t ws_size,
                              hipStream_t stream) {
  const float* x        = (const float*)d_in[0];   // [2,512,4096]
  const float* weight   = (const float*)d_in[1];   // [4096,4096]
  const float* spectrum = (const float*)d_in[2];   // [10000]
  const int*   indices  = (const int*)d_in[3];     // [2,10000]
  float* out = (float*)d_out;                      // [2,512,4096]

  char* ws = (char*)d_ws;
  const size_t WB_BYTES = (size_t)N_DIM * K_DIM * 2;   // 32 MB
  const size_t XB_BYTES = (size_t)M_DIM * K_DIM * 2;   //  8 MB
  const size_t P1_BYTES = (size_t)M_DIM * N_DIM * 4;   // 16 MB per partial

  ushort_t* wb = (ushort_t*)ws;
  ushort_t* xb = (ushort_t*)(ws + WB_BYTES);
  float* part = (float*)(ws + WB_BYTES + XB_BYTES);

  // zsplit=2 measured better than 4 (R1: 48+13 vs R0: 51.5+8 us)
  int zsplit = (ws_size >= WB_BYTES + XB_BYTES + P1_BYTES) ? 2 : 1;

  // build W' (y=0..15) + convert x (y=16) in one dispatch
  build_w4<<<dim3(64, 17), 256, 0, stream>>>(weight, spectrum, indices, x, wb, xb);

  gemm_bt<<<dim3(N_DIM / 128, M_DIM / 128, zsplit), 256, 0, stream>>>(
      xb, wb, out, part, K_DIM / zsplit);
  if (zsplit > 1)
    reduce_n<<<(M_DIM * N_DIM / 4) / 256, 256, 0, stream>>>(out, part, zsplit - 1);
}